// Round 1
// 1019.830 us; speedup vs baseline: 4.4255x; 4.4255x over previous
//
#include <hip/hip_runtime.h>

#define NPTS 100000
#define CCH  128
#define HIMG 480
#define WIMG 640
#define HWSZ (HIMG*WIMG)
// interleaved transposed layout: per pixel 384 floats = [Q c0..127 | GX c0..127 | GY c0..127]
#define TROW 384

struct State {
  double accA[28];   // accepted-pose accums: [0..5]=g, [6..26]=H upper-tri, [27]=sum e·e
  double accC[28];   // candidate-pose accums (fused path)
  double accB;       // candidate cost sum (legacy fallback path)
  double prev_cost;
  float R[9];
  float t[3];
  float Rc[9];
  float tc[3];
  float lam;
  float lr;
};

__device__ State g_st;

__device__ __forceinline__ float sel6(int k, float a0,float a1,float a2,float a3,float a4,float a5){
  float r = a0;
  r = (k==1)?a1:r; r = (k==2)?a2:r; r = (k==3)?a3:r; r = (k==4)?a4:r; r = (k==5)?a5:r;
  return r;
}

__global__ void k_init(){
  if(threadIdx.x==0){
    for(int i=0;i<28;i++){ g_st.accA[i]=0.0; g_st.accC[i]=0.0; }
    g_st.accB=0.0; g_st.prev_cost=0.0;
    g_st.R[0]=1.f; g_st.R[1]=0.f; g_st.R[2]=0.f;
    g_st.R[3]=0.f; g_st.R[4]=1.f; g_st.R[5]=0.f;
    g_st.R[6]=0.f; g_st.R[7]=0.f; g_st.R[8]=1.f;
    g_st.t[0]=1.f; g_st.t[1]=1.f; g_st.t[2]=0.f;
    g_st.lam=0.01f; g_st.lr=0.1f;
  }
}

// ---------------------------------------------------------------------------
// Transpose (C,H,W) x3 -> (pixel, 384) interleaved. 64 pixels per block.
// LDS tile XOR-swizzled so both write (stride-1 per c-row) and read
// (16 pixels x 4 channel-blocks) are <=2-way bank conflicts (free, m136).
// ---------------------------------------------------------------------------
#define TIDX(c,p) ((c)*66 + ((p) ^ ((((c)>>5)&3)<<4)))

__global__ __launch_bounds__(256) void k_transpose(
    const float* __restrict__ Q, const float* __restrict__ GX,
    const float* __restrict__ GY, float* __restrict__ T)
{
  __shared__ float tile[128*66];
  const int pbase = blockIdx.x * 64;   // 640 % 64 == 0 -> never crosses a row
  const int t = threadIdx.x;

  for(int m=0;m<3;m++){
    const float* __restrict__ src = (m==0)?Q:((m==1)?GX:GY);
    __syncthreads();
    // load: thread t loads float4 of pixels; c=(t>>4)+16k, p4=(t&15)*4
    #pragma unroll
    for(int k=0;k<8;k++){
      const int c = (t>>4) + 16*k;
      const float4 v = *reinterpret_cast<const float4*>(src + (size_t)c*HWSZ + pbase + ((t&15)<<2));
      float* d = &tile[TIDX(c, (t&15)<<2)];
      d[0]=v.x; d[1]=v.y; d[2]=v.z; d[3]=v.w;
    }
    __syncthreads();
    // store: thread t owns pixel p=t>>2, channel block cb=(t&3)*32 -> 128B contiguous
    const int p  = t>>2;
    const int cb = (t&3)*32;
    float4* dst = reinterpret_cast<float4*>(T + (size_t)(pbase+p)*TROW + m*128 + cb);
    #pragma unroll
    for(int k=0;k<8;k++){
      float4 v;
      v.x = tile[TIDX(cb+4*k+0, p)];
      v.y = tile[TIDX(cb+4*k+1, p)];
      v.z = tile[TIDX(cb+4*k+2, p)];
      v.w = tile[TIDX(cb+4*k+3, p)];
      dst[k] = v;
    }
  }
}

// ---------------------------------------------------------------------------
// Fused pass over transposed layout: project (pose = accepted or candidate),
// gather coalesced float2 per lane, reduce 6 channel sums, accumulate
// g(6) + H(21) + ee(1) into accA (cand=0) or accC (cand=1).
// ---------------------------------------------------------------------------
__global__ __launch_bounds__(256) void k_pass(
    const float* __restrict__ pts, const float* __restrict__ ref,
    const float* __restrict__ T,   const float* __restrict__ Kin, int cand)
{
  __shared__ double wacc[4][28];
  const int lane = threadIdx.x & 63;
  const int wid  = threadIdx.x >> 6;

  const float fx=Kin[0], cx=Kin[2], fy=Kin[4], cy=Kin[5];
  const float* Rp = cand ? g_st.Rc : g_st.R;
  const float* tp = cand ? g_st.tc : g_st.t;
  const float R00=Rp[0],R01=Rp[1],R02=Rp[2];
  const float R10=Rp[3],R11=Rp[4],R12=Rp[5];
  const float R20=Rp[6],R21=Rp[7],R22=Rp[8];
  const float t0=tp[0],t1=tp[1],t2=tp[2];

  // lane -> owned accumulator component
  int role = 3, ci = 0, cj = 0;
  if(lane < 6){ role = 0; ci = lane; cj = lane; }
  else if(lane < 27){
    role = 1;
    const int tt = lane - 6;
    int i = 5;
    i = (tt < 20) ? 4 : i;
    i = (tt < 18) ? 3 : i;
    i = (tt < 15) ? 2 : i;
    i = (tt < 11) ? 1 : i;
    i = (tt <  6) ? 0 : i;
    const int rs = (i==0)?0:(i==1)?6:(i==2)?11:(i==3)?15:(i==4)?18:20;
    ci = i; cj = i + (tt - rs);
  }
  else if(lane == 27){ role = 2; }

  double acc = 0.0;
  const int c0 = lane*2;
  const int wstride = gridDim.x*4;
  for(int n = blockIdx.x*4 + wid; n < NPTS; n += wstride){
    const float X=pts[3*n], Y=pts[3*n+1], Z=pts[3*n+2];
    const float x = R00*X + R01*Y + R02*Z + t0;
    const float y = R10*X + R11*Y + R12*Z + t1;
    const float z = R20*X + R21*Y + R22*Z + t2;
    const float uu = fx*x + cx*z;
    const float vv = fy*y + cy*z;
    const int pjx = (int)rintf(uu/z) - 1;
    const int pjy = (int)rintf(vv/z) - 1;
    const int jj = pjx<0?0:(pjx>(WIMG-1)?(WIMG-1):pjx);
    const int ii = pjy<0?0:(pjy>(HIMG-1)?(HIMG-1):pjy);
    const int idx = ii*WIMG + jj;

    const float* base = T + (size_t)idx*TROW + c0;
    const float2 qq = *reinterpret_cast<const float2*>(base);
    const float2 gg = *reinterpret_cast<const float2*>(base + 128);
    const float2 hh = *reinterpret_cast<const float2*>(base + 256);
    const float2 rr = *reinterpret_cast<const float2*>(ref + n*CCH + c0);
    const float e0 = qq.x-rr.x, e1 = qq.y-rr.y;

    float see = e0*e0 + e1*e1;
    float sb1 = gg.x*e0 + gg.y*e1;
    float sb2 = hh.x*e0 + hh.y*e1;
    float sa11= gg.x*gg.x + gg.y*gg.y;
    float sa12= gg.x*hh.x + gg.y*hh.y;
    float sa22= hh.x*hh.x + hh.y*hh.y;
    #pragma unroll
    for(int m=1;m<64;m<<=1){
      see += __shfl_xor(see,m);
      sb1 += __shfl_xor(sb1,m);
      sb2 += __shfl_xor(sb2,m);
      sa11+= __shfl_xor(sa11,m);
      sa12+= __shfl_xor(sa12,m);
      sa22+= __shfl_xor(sa22,m);
    }

    const float iz = 1.0f/z;
    const float ux = x*iz, vy = y*iz;
    const float m00=fx*iz, m01=0.f,    m02=-fx*ux*iz, m03=-fx*ux*vy,       m04=fx*(1.f+ux*ux), m05=-fx*vy;
    const float m10=0.f,   m11=fy*iz,  m12=-fy*vy*iz, m13=-fy*(1.f+vy*vy), m14=fy*ux*vy,       m15=fy*ux;

    float contrib;
    if(role==0){
      const float M0=sel6(ci,m00,m01,m02,m03,m04,m05);
      const float M1=sel6(ci,m10,m11,m12,m13,m14,m15);
      contrib = M0*sb1 + M1*sb2;
    } else if(role==1){
      const float M0i=sel6(ci,m00,m01,m02,m03,m04,m05);
      const float M1i=sel6(ci,m10,m11,m12,m13,m14,m15);
      const float M0j=sel6(cj,m00,m01,m02,m03,m04,m05);
      const float M1j=sel6(cj,m10,m11,m12,m13,m14,m15);
      contrib = sa11*(M0i*M0j) + sa12*(M0i*M1j + M1i*M0j) + sa22*(M1i*M1j);
    } else if(role==2){
      contrib = see;
    } else {
      contrib = 0.f;
    }
    acc += (double)contrib;
  }

  if(lane<28) wacc[wid][lane] = acc;
  __syncthreads();
  if(threadIdx.x<28){
    double s = wacc[0][threadIdx.x]+wacc[1][threadIdx.x]+wacc[2][threadIdx.x]+wacc[3][threadIdx.x];
    atomicAdd(cand ? &g_st.accC[threadIdx.x] : &g_st.accA[threadIdx.x], s);
  }
}

// LM accept/reject for fused path: cost from accC[27]; on accept adopt accC
// as the accepted-pose accums (identical math to re-running accum at the
// accepted pose). Zeroes accC.
__global__ void k_update2(){
  if(threadIdx.x!=0) return;
  const double new_cost = 0.5*g_st.accC[27]/(double)NPTS;
  const bool worse = new_cost > g_st.prev_cost;
  float lam = g_st.lam * (worse?10.0f:0.1f);
  g_st.lam = fminf(fmaxf(lam,1e-6f),10000.0f);
  g_st.lr  = worse ? fminf(fmaxf(0.1f*g_st.lr,0.001f),1.0f) : 0.1f;
  if(!worse){
    for(int i=0;i<28;i++) g_st.accA[i]=g_st.accC[i];
    for(int i=0;i<9;i++) g_st.R[i]=g_st.Rc[i];
    for(int i=0;i<3;i++) g_st.t[i]=g_st.tc[i];
    g_st.prev_cost = new_cost;
  }
  for(int i=0;i<28;i++) g_st.accC[i]=0.0;
}

// ---------------------------------------------------------------------------
// Legacy fallback path (verified): direct (C,H,W) gathers.
// ---------------------------------------------------------------------------
__global__ __launch_bounds__(256) void k_accum(
    const float* __restrict__ pts, const float* __restrict__ ref,
    const float* __restrict__ Q,   const float* __restrict__ GX,
    const float* __restrict__ GY,  const float* __restrict__ Kin)
{
  __shared__ double wacc[4][28];
  const int lane = threadIdx.x & 63;
  const int wid  = threadIdx.x >> 6;

  const float fx=Kin[0], cx=Kin[2], fy=Kin[4], cy=Kin[5];
  const float R00=g_st.R[0],R01=g_st.R[1],R02=g_st.R[2];
  const float R10=g_st.R[3],R11=g_st.R[4],R12=g_st.R[5];
  const float R20=g_st.R[6],R21=g_st.R[7],R22=g_st.R[8];
  const float t0=g_st.t[0],t1=g_st.t[1],t2=g_st.t[2];

  int role = 3, ci = 0, cj = 0;
  if(lane < 6){ role = 0; ci = lane; cj = lane; }
  else if(lane < 27){
    role = 1;
    const int tt = lane - 6;
    int i = 5;
    i = (tt < 20) ? 4 : i;
    i = (tt < 18) ? 3 : i;
    i = (tt < 15) ? 2 : i;
    i = (tt < 11) ? 1 : i;
    i = (tt <  6) ? 0 : i;
    const int rs = (i==0)?0:(i==1)?6:(i==2)?11:(i==3)?15:(i==4)?18:20;
    ci = i; cj = i + (tt - rs);
  }
  else if(lane == 27){ role = 2; }

  double acc = 0.0;
  const int c0 = lane*2;
  const int wstride = gridDim.x*4;
  for(int n = blockIdx.x*4 + wid; n < NPTS; n += wstride){
    const float X=pts[3*n], Y=pts[3*n+1], Z=pts[3*n+2];
    const float x = R00*X + R01*Y + R02*Z + t0;
    const float y = R10*X + R11*Y + R12*Z + t1;
    const float z = R20*X + R21*Y + R22*Z + t2;
    const float uu = fx*x + cx*z;
    const float vv = fy*y + cy*z;
    const int pjx = (int)rintf(uu/z) - 1;
    const int pjy = (int)rintf(vv/z) - 1;
    const int jj = pjx<0?0:(pjx>(WIMG-1)?(WIMG-1):pjx);
    const int ii = pjy<0?0:(pjy>(HIMG-1)?(HIMG-1):pjy);
    const int idx = ii*WIMG + jj;

    const int o0 = c0*HWSZ + idx;
    const float q0 = Q[o0],  q1 = Q[o0+HWSZ];
    const float gx0= GX[o0], gx1= GX[o0+HWSZ];
    const float gy0= GY[o0], gy1= GY[o0+HWSZ];
    const float2 rr = *reinterpret_cast<const float2*>(ref + n*CCH + c0);
    const float e0 = q0-rr.x, e1 = q1-rr.y;

    float see = e0*e0 + e1*e1;
    float sb1 = gx0*e0 + gx1*e1;
    float sb2 = gy0*e0 + gy1*e1;
    float sa11= gx0*gx0 + gx1*gx1;
    float sa12= gx0*gy0 + gx1*gy1;
    float sa22= gy0*gy0 + gy1*gy1;
    #pragma unroll
    for(int m=1;m<64;m<<=1){
      see += __shfl_xor(see,m);
      sb1 += __shfl_xor(sb1,m);
      sb2 += __shfl_xor(sb2,m);
      sa11+= __shfl_xor(sa11,m);
      sa12+= __shfl_xor(sa12,m);
      sa22+= __shfl_xor(sa22,m);
    }

    const float iz = 1.0f/z;
    const float ux = x*iz, vy = y*iz;
    const float m00=fx*iz, m01=0.f,    m02=-fx*ux*iz, m03=-fx*ux*vy,       m04=fx*(1.f+ux*ux), m05=-fx*vy;
    const float m10=0.f,   m11=fy*iz,  m12=-fy*vy*iz, m13=-fy*(1.f+vy*vy), m14=fy*ux*vy,       m15=fy*ux;

    float contrib;
    if(role==0){
      const float M0=sel6(ci,m00,m01,m02,m03,m04,m05);
      const float M1=sel6(ci,m10,m11,m12,m13,m14,m15);
      contrib = M0*sb1 + M1*sb2;
    } else if(role==1){
      const float M0i=sel6(ci,m00,m01,m02,m03,m04,m05);
      const float M1i=sel6(ci,m10,m11,m12,m13,m14,m15);
      const float M0j=sel6(cj,m00,m01,m02,m03,m04,m05);
      const float M1j=sel6(cj,m10,m11,m12,m13,m14,m15);
      contrib = sa11*(M0i*M0j) + sa12*(M0i*M1j + M1i*M0j) + sa22*(M1i*M1j);
    } else if(role==2){
      contrib = see;
    } else {
      contrib = 0.f;
    }
    acc += (double)contrib;
  }

  if(lane<28) wacc[wid][lane] = acc;
  __syncthreads();
  if(threadIdx.x<28){
    double s = wacc[0][threadIdx.x]+wacc[1][threadIdx.x]+wacc[2][threadIdx.x]+wacc[3][threadIdx.x];
    atomicAdd(&g_st.accA[threadIdx.x], s);
  }
}

__global__ __launch_bounds__(256) void k_cost(
    const float* __restrict__ pts, const float* __restrict__ ref,
    const float* __restrict__ Q,   const float* __restrict__ Kin)
{
  __shared__ double wacc[4];
  const int lane = threadIdx.x & 63;
  const int wid  = threadIdx.x >> 6;

  const float fx=Kin[0], cx=Kin[2], fy=Kin[4], cy=Kin[5];
  const float R00=g_st.Rc[0],R01=g_st.Rc[1],R02=g_st.Rc[2];
  const float R10=g_st.Rc[3],R11=g_st.Rc[4],R12=g_st.Rc[5];
  const float R20=g_st.Rc[6],R21=g_st.Rc[7],R22=g_st.Rc[8];
  const float t0=g_st.tc[0],t1=g_st.tc[1],t2=g_st.tc[2];

  double acc = 0.0;
  const int c0 = lane*2;
  const int wstride = gridDim.x*4;
  for(int n = blockIdx.x*4 + wid; n < NPTS; n += wstride){
    const float X=pts[3*n], Y=pts[3*n+1], Z=pts[3*n+2];
    const float x = R00*X + R01*Y + R02*Z + t0;
    const float y = R10*X + R11*Y + R12*Z + t1;
    const float z = R20*X + R21*Y + R22*Z + t2;
    const float uu = fx*x + cx*z;
    const float vv = fy*y + cy*z;
    const int pjx = (int)rintf(uu/z) - 1;
    const int pjy = (int)rintf(vv/z) - 1;
    const int jj = pjx<0?0:(pjx>(WIMG-1)?(WIMG-1):pjx);
    const int ii = pjy<0?0:(pjy>(HIMG-1)?(HIMG-1):pjy);
    const int idx = ii*WIMG + jj;

    const int o0 = c0*HWSZ + idx;
    const float q0 = Q[o0], q1 = Q[o0+HWSZ];
    const float2 rr = *reinterpret_cast<const float2*>(ref + n*CCH + c0);
    const float e0 = q0-rr.x, e1 = q1-rr.y;
    float see = e0*e0 + e1*e1;
    #pragma unroll
    for(int m=1;m<64;m<<=1) see += __shfl_xor(see,m);
    if(lane==0) acc += (double)see;
  }
  if(lane==0) wacc[wid]=acc;
  __syncthreads();
  if(threadIdx.x==0) atomicAdd(&g_st.accB, wacc[0]+wacc[1]+wacc[2]+wacc[3]);
}

// Single-thread: build Hd, solve 6x6, so3exp, candidate pose. Zeroes accB.
__global__ void k_solve(int iter){
  if(threadIdx.x!=0) return;
  const double cost_mean = 0.5*g_st.accA[27]/(double)NPTS;
  if(iter==0) g_st.prev_cost = cost_mean;
  const double lam = (double)g_st.lam;

  double Hm[6][6];
  int m=0;
  for(int i=0;i<6;i++) for(int j=i;j<6;j++){ double v=g_st.accA[6+m]; m++; Hm[i][j]=v; Hm[j][i]=v; }
  double A[6][7];
  for(int i=0;i<6;i++){
    for(int j=0;j<6;j++) A[i][j]=Hm[i][j];
    A[i][i] = Hm[i][i] + lam*(Hm[i][i]+1e-9);
    A[i][6] = g_st.accA[i];
  }
  for(int k=0;k<6;k++){
    int piv=k; double mx=fabs(A[k][k]);
    for(int r=k+1;r<6;r++){ double v=fabs(A[r][k]); if(v>mx){mx=v;piv=r;} }
    if(piv!=k){ for(int c=k;c<7;c++){ double tmp=A[k][c]; A[k][c]=A[piv][c]; A[piv][c]=tmp; } }
    const double inv = 1.0/A[k][k];
    for(int r=k+1;r<6;r++){
      const double f = A[r][k]*inv;
      for(int c=k;c<7;c++) A[r][c] -= f*A[k][c];
    }
  }
  double xsol[6];
  for(int r=5;r>=0;r--){
    double s=A[r][6];
    for(int c=r+1;c<6;c++) s -= A[r][c]*xsol[c];
    xsol[r]=s/A[r][r];
  }
  const double lr = (double)g_st.lr;
  float d[6];
  for(int k=0;k<6;k++) d[k] = (float)(-lr*xsol[k]);

  const float wx=d[3], wy=d[4], wz=d[5];
  const float th2 = wx*wx+wy*wy+wz*wz;
  const float theta = sqrtf(th2);
  const bool small = theta < 1e-7f;
  const float th = small?1.0f:theta;
  const float Aa = small?1.0f:(sinf(th)/th);
  const float Bb = small?0.5f:((1.0f-cosf(th))/(th*th));
  float Wm[3][3] = {{0.f,-wz,wy},{wz,0.f,-wx},{-wy,wx,0.f}};
  float W2[3][3];
  for(int i=0;i<3;i++) for(int j=0;j<3;j++)
    W2[i][j] = Wm[i][0]*Wm[0][j] + Wm[i][1]*Wm[1][j] + Wm[i][2]*Wm[2][j];
  float dR[3][3];
  for(int i=0;i<3;i++) for(int j=0;j<3;j++)
    dR[i][j] = (i==j?1.f:0.f) + Aa*Wm[i][j] + Bb*W2[i][j];

  float Rn[9], tn[3];
  for(int i=0;i<3;i++){
    for(int j=0;j<3;j++)
      Rn[i*3+j] = dR[i][0]*g_st.R[0*3+j] + dR[i][1]*g_st.R[1*3+j] + dR[i][2]*g_st.R[2*3+j];
    tn[i] = dR[i][0]*g_st.t[0] + dR[i][1]*g_st.t[1] + dR[i][2]*g_st.t[2] + d[i];
  }
  for(int i=0;i<9;i++) g_st.Rc[i]=Rn[i];
  for(int i=0;i<3;i++) g_st.tc[i]=tn[i];
  g_st.accB = 0.0;
}

// Legacy update (fallback path). Zeroes accA.
__global__ void k_update(){
  if(threadIdx.x!=0) return;
  const double new_cost = 0.5*g_st.accB/(double)NPTS;
  const bool worse = new_cost > g_st.prev_cost;
  float lam = g_st.lam * (worse?10.0f:0.1f);
  lam = fminf(fmaxf(lam,1e-6f),10000.0f);
  g_st.lam = lam;
  g_st.lr  = worse ? fminf(fmaxf(0.1f*g_st.lr,0.001f),1.0f) : 0.1f;
  if(!worse){
    for(int i=0;i<9;i++) g_st.R[i]=g_st.Rc[i];
    for(int i=0;i<3;i++) g_st.t[i]=g_st.tc[i];
    g_st.prev_cost = new_cost;
  }
  for(int i=0;i<28;i++) g_st.accA[i]=0.0;
}

__global__ void k_write(float* __restrict__ out, int out_size){
  const int i = threadIdx.x;
  if(i<9 && i<out_size) out[i]=g_st.R[i];
  else if(i<12 && i<out_size) out[i]=g_st.t[i-9];
}

extern "C" void kernel_launch(void* const* d_in, const int* in_sizes, int n_in,
                              void* d_out, int out_size, void* d_ws, size_t ws_size,
                              hipStream_t stream) {
  const float* pts = (const float*)d_in[0];
  const float* ref = (const float*)d_in[1];
  const float* Q   = (const float*)d_in[2];
  const float* GX  = (const float*)d_in[3];
  const float* GY  = (const float*)d_in[4];
  const float* Km  = (const float*)d_in[5];
  float* out = (float*)d_out;

  const size_t need = (size_t)HWSZ * TROW * sizeof(float); // ~472 MB
  const int GRID = 2048;

  if(d_ws != nullptr && ws_size >= need){
    float* T = (float*)d_ws;
    k_init<<<1,64,0,stream>>>();
    k_transpose<<<HWSZ/64,256,0,stream>>>(Q,GX,GY,T);
    k_pass<<<GRID,256,0,stream>>>(pts,ref,T,Km,0);      // accums at initial pose -> accA
    for(int i=0;i<5;i++){
      k_solve<<<1,64,0,stream>>>(i);                    // candidate pose from accA
      k_pass<<<GRID,256,0,stream>>>(pts,ref,T,Km,1);    // fused cost+accums at candidate -> accC
      k_update2<<<1,64,0,stream>>>();                   // accept: accA<-accC, pose<-candidate
    }
    k_write<<<1,64,0,stream>>>(out,out_size);
  } else {
    // fallback: verified legacy path (no workspace layout transform)
    k_init<<<1,64,0,stream>>>();
    for(int i=0;i<5;i++){
      k_accum<<<GRID,256,0,stream>>>(pts,ref,Q,GX,GY,Km);
      k_solve<<<1,64,0,stream>>>(i);
      k_cost<<<GRID,256,0,stream>>>(pts,ref,Q,Km);
      k_update<<<1,64,0,stream>>>();
    }
    k_write<<<1,64,0,stream>>>(out,out_size);
  }
}

// Round 2
// 997.997 us; speedup vs baseline: 4.5224x; 1.0219x over previous
//
#include <hip/hip_runtime.h>

#define NPTS 100000
#define CCH  128
#define HIMG 480
#define WIMG 640
#define HWSZ (HIMG*WIMG)
// interleaved transposed layout: per pixel 384 floats = [Q c0..127 | GX c0..127 | GY c0..127]
#define TROW 384
#define NSLOT 8

struct State {
  double slotsA[NSLOT][28]; // accepted-pose accums (8-way slotted): [0..5]=g, [6..26]=H ut, [27]=ee
  double slotsC[NSLOT][28]; // candidate-pose accums
  double accA[28];          // legacy fallback
  double accB;              // legacy fallback
  double prev_cost;
  float R[9];
  float t[3];
  float Rc[9];
  float tc[3];
  float lam;
  float lr;
};

__device__ State g_st;

// upper-tri index: entries before row i = 6i - i(i-1)/2
#define HIDX(i,j) (6 + (6*(i)) - ((i)*((i)-1))/2 + ((j)-(i)))

__device__ __forceinline__ float sel6(int k, float a0,float a1,float a2,float a3,float a4,float a5){
  float r = a0;
  r = (k==1)?a1:r; r = (k==2)?a2:r; r = (k==3)?a3:r; r = (k==4)?a4:r; r = (k==5)?a5:r;
  return r;
}

// ---------------------------------------------------------------------------
// Transpose (C,H,W) x3 -> (pixel, 384). 32 pixels x 128 channels per block,
// one map per block. LDS [pixel][channel] pad-132 + (p>>2)-keyed XOR swizzle:
// scalar writes <=2-way conflict, b128 reads at throughput floor.
// Block 0 / thread 0 also (re)initializes g_st (no other g_st use here).
// ---------------------------------------------------------------------------
#define TP_PIX 32
#define NTILE (HWSZ/TP_PIX)   // 9600
#define TIX(p,c) ((p)*132 + ((c) ^ ((((p)>>2)&3)<<3)))

__global__ __launch_bounds__(256) void k_transpose(
    const float* __restrict__ Q, const float* __restrict__ GX,
    const float* __restrict__ GY, float* __restrict__ T)
{
  if(blockIdx.x==0 && threadIdx.x==0){
    for(int s=0;s<NSLOT;s++) for(int k=0;k<28;k++){ g_st.slotsA[s][k]=0.0; g_st.slotsC[s][k]=0.0; }
    g_st.prev_cost=0.0;
    g_st.R[0]=1.f; g_st.R[1]=0.f; g_st.R[2]=0.f;
    g_st.R[3]=0.f; g_st.R[4]=1.f; g_st.R[5]=0.f;
    g_st.R[6]=0.f; g_st.R[7]=0.f; g_st.R[8]=1.f;
    g_st.t[0]=1.f; g_st.t[1]=1.f; g_st.t[2]=0.f;
    g_st.lam=0.01f; g_st.lr=0.1f;
  }

  __shared__ float tile[TP_PIX*132];
  const int bid = blockIdx.x;
  const int m   = bid / NTILE;
  const int tl  = bid - m*NTILE;
  const int pbase = tl*TP_PIX;
  const float* __restrict__ src = (m==0)?Q:((m==1)?GX:GY);
  const int t = threadIdx.x;

  // load: thread t reads float4 of 4 pixels at channel c; 8 c-rows x 128B per wave instr
  const int c_lo = t>>3;          // 0..31
  const int p4   = (t&7)<<2;      // 0,4,...,28
  #pragma unroll
  for(int k=0;k<4;k++){
    const int c = c_lo + 32*k;
    const float4 v = *reinterpret_cast<const float4*>(src + (size_t)c*HWSZ + pbase + p4);
    tile[TIX(p4+0,c)] = v.x;
    tile[TIX(p4+1,c)] = v.y;
    tile[TIX(p4+2,c)] = v.z;
    tile[TIX(p4+3,c)] = v.w;
  }
  __syncthreads();
  // store: thread t owns pixel p, 4 float4 channel chunks; 8 lanes cover 128B contiguous
  const int p = t>>3;             // 0..31
  const int a = t&7;
  float* dstp = T + (size_t)(pbase+p)*TROW + m*128;
  #pragma unroll
  for(int q=0;q<4;q++){
    const int ch = a*4 + 32*q;
    const float4 v = *reinterpret_cast<const float4*>(&tile[TIX(p,ch)]);
    *reinterpret_cast<float4*>(dstp + ch) = v;
  }
}

// ---------------------------------------------------------------------------
// Pass: project (accepted or candidate pose), coalesced float2 gathers,
// PER-LANE fp32 accumulation of all 28 components (linearity of g/H/ee in the
// channel sums) -- no per-point cross-lane ops. One double butterfly at end.
// ---------------------------------------------------------------------------
__global__ __launch_bounds__(256) void k_pass(
    const float* __restrict__ pts, const float* __restrict__ ref,
    const float* __restrict__ T,   const float* __restrict__ Kin, int cand)
{
  __shared__ double wacc[4][28];
  const int lane = threadIdx.x & 63;
  const int wid  = threadIdx.x >> 6;

  const float fx=Kin[0], cx=Kin[2], fy=Kin[4], cy=Kin[5];
  const float* Rp = cand ? g_st.Rc : g_st.R;
  const float* tp = cand ? g_st.tc : g_st.t;
  const float R00=Rp[0],R01=Rp[1],R02=Rp[2];
  const float R10=Rp[3],R11=Rp[4],R12=Rp[5];
  const float R20=Rp[6],R21=Rp[7],R22=Rp[8];
  const float t0=tp[0],t1=tp[1],t2=tp[2];

  float a[28];
  #pragma unroll
  for(int k=0;k<28;k++) a[k]=0.f;

  const int c0 = lane*2;
  const int wstride = gridDim.x*4;
  for(int n = blockIdx.x*4 + wid; n < NPTS; n += wstride){
    const float X=pts[3*n], Y=pts[3*n+1], Z=pts[3*n+2];
    const float x = R00*X + R01*Y + R02*Z + t0;
    const float y = R10*X + R11*Y + R12*Z + t1;
    const float z = R20*X + R21*Y + R22*Z + t2;
    const float uu = fx*x + cx*z;
    const float vv = fy*y + cy*z;
    const int pjx = (int)rintf(uu/z) - 1;
    const int pjy = (int)rintf(vv/z) - 1;
    const int jj = pjx<0?0:(pjx>(WIMG-1)?(WIMG-1):pjx);
    const int ii = pjy<0?0:(pjy>(HIMG-1)?(HIMG-1):pjy);
    const int idx = ii*WIMG + jj;

    const float* base = T + (size_t)idx*TROW + c0;
    const float2 qq = *reinterpret_cast<const float2*>(base);
    const float2 gg = *reinterpret_cast<const float2*>(base + 128);
    const float2 hh = *reinterpret_cast<const float2*>(base + 256);
    const float2 rr = *reinterpret_cast<const float2*>(ref + n*CCH + c0);
    const float e0 = qq.x-rr.x, e1 = qq.y-rr.y;

    // per-lane channel partials (2 channels each)
    const float see = e0*e0 + e1*e1;
    const float sb1 = gg.x*e0 + gg.y*e1;
    const float sb2 = hh.x*e0 + hh.y*e1;
    const float sa11= gg.x*gg.x + gg.y*gg.y;
    const float sa12= gg.x*hh.x + gg.y*hh.y;
    const float sa22= hh.x*hh.x + hh.y*hh.y;

    // M = J_px_p @ [I | -skew(p)]  (2x6), uniform across wave
    const float iz = 1.0f/z;
    const float ux = x*iz, vy = y*iz;
    float M0[6], M1[6];
    M0[0]=fx*iz; M0[1]=0.f;   M0[2]=-fx*ux*iz; M0[3]=-fx*ux*vy;       M0[4]=fx*(1.f+ux*ux); M0[5]=-fx*vy;
    M1[0]=0.f;   M1[1]=fy*iz; M1[2]=-fy*vy*iz; M1[3]=-fy*(1.f+vy*vy); M1[4]=fy*ux*vy;       M1[5]=fy*ux;

    #pragma unroll
    for(int i=0;i<6;i++) a[i] += M0[i]*sb1 + M1[i]*sb2;
    #pragma unroll
    for(int i=0;i<6;i++){
      #pragma unroll
      for(int j=i;j<6;j++){
        a[HIDX(i,j)] += sa11*(M0[i]*M0[j]) + sa12*(M0[i]*M1[j]+M1[i]*M0[j]) + sa22*(M1[i]*M1[j]);
      }
    }
    a[27] += see;
  }

  // once-per-kernel reduction: double butterfly per component, then block sum
  #pragma unroll
  for(int k=0;k<28;k++){
    double v = (double)a[k];
    #pragma unroll
    for(int m=1;m<64;m<<=1) v += __shfl_xor(v,m);
    if(lane==0) wacc[wid][k]=v;
  }
  __syncthreads();
  if(threadIdx.x<28){
    double s = wacc[0][threadIdx.x]+wacc[1][threadIdx.x]+wacc[2][threadIdx.x]+wacc[3][threadIdx.x];
    double* slot = cand ? g_st.slotsC[blockIdx.x & (NSLOT-1)] : g_st.slotsA[blockIdx.x & (NSLOT-1)];
    atomicAdd(&slot[threadIdx.x], s);
  }
}

// ---------------------------------------------------------------------------
// Fused step: (iter>0: LM accept/reject from slotsC) then solve -> candidate.
// ---------------------------------------------------------------------------
__global__ void k_step(int iter){
  __shared__ double red[28];  // accums to solve from (post-update accepted)
  __shared__ double sC[28];
  const int t = threadIdx.x;
  if(t<28){
    double c=0.0, aa=0.0;
    for(int s=0;s<NSLOT;s++){ c += g_st.slotsC[s][t]; aa += g_st.slotsA[s][t]; }
    sC[t]=c; red[t]=aa;
  }
  __syncthreads();
  if(t!=0) return;

  if(iter>0){
    const double new_cost = 0.5*sC[27]/(double)NPTS;
    const bool worse = new_cost > g_st.prev_cost;
    float lam = g_st.lam * (worse?10.0f:0.1f);
    g_st.lam = fminf(fmaxf(lam,1e-6f),10000.0f);
    g_st.lr  = worse ? fminf(fmaxf(0.1f*g_st.lr,0.001f),1.0f) : 0.1f;
    if(!worse){
      for(int k=0;k<28;k++){
        red[k]=sC[k];
        g_st.slotsA[0][k]=sC[k];
        for(int s=1;s<NSLOT;s++) g_st.slotsA[s][k]=0.0;
      }
      for(int i=0;i<9;i++) g_st.R[i]=g_st.Rc[i];
      for(int i=0;i<3;i++) g_st.t[i]=g_st.tc[i];
      g_st.prev_cost = new_cost;
    }
    for(int s=0;s<NSLOT;s++) for(int k=0;k<28;k++) g_st.slotsC[s][k]=0.0;
  } else {
    g_st.prev_cost = 0.5*red[27]/(double)NPTS;
  }

  // ---- solve 6x6 from red[] ----
  const double lam = (double)g_st.lam;
  double Hm[6][6];
  int m=0;
  for(int i=0;i<6;i++) for(int j=i;j<6;j++){ double v=red[6+m]; m++; Hm[i][j]=v; Hm[j][i]=v; }
  double A[6][7];
  for(int i=0;i<6;i++){
    for(int j=0;j<6;j++) A[i][j]=Hm[i][j];
    A[i][i] = Hm[i][i] + lam*(Hm[i][i]+1e-9);
    A[i][6] = red[i];
  }
  for(int k=0;k<6;k++){
    int piv=k; double mx=fabs(A[k][k]);
    for(int r=k+1;r<6;r++){ double v=fabs(A[r][k]); if(v>mx){mx=v;piv=r;} }
    if(piv!=k){ for(int c=k;c<7;c++){ double tmp=A[k][c]; A[k][c]=A[piv][c]; A[piv][c]=tmp; } }
    const double inv = 1.0/A[k][k];
    for(int r=k+1;r<6;r++){
      const double f = A[r][k]*inv;
      for(int c=k;c<7;c++) A[r][c] -= f*A[k][c];
    }
  }
  double xsol[6];
  for(int r=5;r>=0;r--){
    double s=A[r][6];
    for(int c=r+1;c<6;c++) s -= A[r][c]*xsol[c];
    xsol[r]=s/A[r][r];
  }
  const double lr = (double)g_st.lr;
  float d[6];
  for(int k=0;k<6;k++) d[k] = (float)(-lr*xsol[k]);

  const float wx=d[3], wy=d[4], wz=d[5];
  const float th2 = wx*wx+wy*wy+wz*wz;
  const float theta = sqrtf(th2);
  const bool small = theta < 1e-7f;
  const float th = small?1.0f:theta;
  const float Aa = small?1.0f:(sinf(th)/th);
  const float Bb = small?0.5f:((1.0f-cosf(th))/(th*th));
  float Wm[3][3] = {{0.f,-wz,wy},{wz,0.f,-wx},{-wy,wx,0.f}};
  float W2[3][3];
  for(int i=0;i<3;i++) for(int j=0;j<3;j++)
    W2[i][j] = Wm[i][0]*Wm[0][j] + Wm[i][1]*Wm[1][j] + Wm[i][2]*Wm[2][j];
  float dR[3][3];
  for(int i=0;i<3;i++) for(int j=0;j<3;j++)
    dR[i][j] = (i==j?1.f:0.f) + Aa*Wm[i][j] + Bb*W2[i][j];

  float Rn[9], tn[3];
  for(int i=0;i<3;i++){
    for(int j=0;j<3;j++)
      Rn[i*3+j] = dR[i][0]*g_st.R[0*3+j] + dR[i][1]*g_st.R[1*3+j] + dR[i][2]*g_st.R[2*3+j];
    tn[i] = dR[i][0]*g_st.t[0] + dR[i][1]*g_st.t[1] + dR[i][2]*g_st.t[2] + d[i];
  }
  for(int i=0;i<9;i++) g_st.Rc[i]=Rn[i];
  for(int i=0;i<3;i++) g_st.tc[i]=tn[i];
}

// Final: accept/reject last candidate, write output.
__global__ void k_finish(float* __restrict__ out, int out_size){
  const int t = threadIdx.x;
  if(t==0){
    double c=0.0; for(int s=0;s<NSLOT;s++) c += g_st.slotsC[s][27];
    const double new_cost = 0.5*c/(double)NPTS;
    if(!(new_cost > g_st.prev_cost)){
      for(int i=0;i<9;i++) g_st.R[i]=g_st.Rc[i];
      for(int i=0;i<3;i++) g_st.t[i]=g_st.tc[i];
    }
  }
  __syncthreads();
  if(t<9 && t<out_size) out[t]=g_st.R[t];
  else if(t<12 && t<out_size) out[t]=g_st.t[t-9];
}

// ---------------------------------------------------------------------------
// Legacy fallback path (verified): direct (C,H,W) gathers, no workspace.
// ---------------------------------------------------------------------------
__global__ void k_init(){
  if(threadIdx.x==0){
    for(int i=0;i<28;i++) g_st.accA[i]=0.0;
    g_st.accB=0.0; g_st.prev_cost=0.0;
    g_st.R[0]=1.f; g_st.R[1]=0.f; g_st.R[2]=0.f;
    g_st.R[3]=0.f; g_st.R[4]=1.f; g_st.R[5]=0.f;
    g_st.R[6]=0.f; g_st.R[7]=0.f; g_st.R[8]=1.f;
    g_st.t[0]=1.f; g_st.t[1]=1.f; g_st.t[2]=0.f;
    g_st.lam=0.01f; g_st.lr=0.1f;
  }
}

__global__ __launch_bounds__(256) void k_accum(
    const float* __restrict__ pts, const float* __restrict__ ref,
    const float* __restrict__ Q,   const float* __restrict__ GX,
    const float* __restrict__ GY,  const float* __restrict__ Kin)
{
  __shared__ double wacc[4][28];
  const int lane = threadIdx.x & 63;
  const int wid  = threadIdx.x >> 6;

  const float fx=Kin[0], cx=Kin[2], fy=Kin[4], cy=Kin[5];
  const float R00=g_st.R[0],R01=g_st.R[1],R02=g_st.R[2];
  const float R10=g_st.R[3],R11=g_st.R[4],R12=g_st.R[5];
  const float R20=g_st.R[6],R21=g_st.R[7],R22=g_st.R[8];
  const float t0=g_st.t[0],t1=g_st.t[1],t2=g_st.t[2];

  int role = 3, ci = 0, cj = 0;
  if(lane < 6){ role = 0; ci = lane; cj = lane; }
  else if(lane < 27){
    role = 1;
    const int tt = lane - 6;
    int i = 5;
    i = (tt < 20) ? 4 : i;
    i = (tt < 18) ? 3 : i;
    i = (tt < 15) ? 2 : i;
    i = (tt < 11) ? 1 : i;
    i = (tt <  6) ? 0 : i;
    const int rs = (i==0)?0:(i==1)?6:(i==2)?11:(i==3)?15:(i==4)?18:20;
    ci = i; cj = i + (tt - rs);
  }
  else if(lane == 27){ role = 2; }

  double acc = 0.0;
  const int c0 = lane*2;
  const int wstride = gridDim.x*4;
  for(int n = blockIdx.x*4 + wid; n < NPTS; n += wstride){
    const float X=pts[3*n], Y=pts[3*n+1], Z=pts[3*n+2];
    const float x = R00*X + R01*Y + R02*Z + t0;
    const float y = R10*X + R11*Y + R12*Z + t1;
    const float z = R20*X + R21*Y + R22*Z + t2;
    const float uu = fx*x + cx*z;
    const float vv = fy*y + cy*z;
    const int pjx = (int)rintf(uu/z) - 1;
    const int pjy = (int)rintf(vv/z) - 1;
    const int jj = pjx<0?0:(pjx>(WIMG-1)?(WIMG-1):pjx);
    const int ii = pjy<0?0:(pjy>(HIMG-1)?(HIMG-1):pjy);
    const int idx = ii*WIMG + jj;

    const int o0 = c0*HWSZ + idx;
    const float q0 = Q[o0],  q1 = Q[o0+HWSZ];
    const float gx0= GX[o0], gx1= GX[o0+HWSZ];
    const float gy0= GY[o0], gy1= GY[o0+HWSZ];
    const float2 rr = *reinterpret_cast<const float2*>(ref + n*CCH + c0);
    const float e0 = q0-rr.x, e1 = q1-rr.y;

    float see = e0*e0 + e1*e1;
    float sb1 = gx0*e0 + gx1*e1;
    float sb2 = gy0*e0 + gy1*e1;
    float sa11= gx0*gx0 + gx1*gx1;
    float sa12= gx0*gy0 + gx1*gy1;
    float sa22= gy0*gy0 + gy1*gy1;
    #pragma unroll
    for(int m=1;m<64;m<<=1){
      see += __shfl_xor(see,m);
      sb1 += __shfl_xor(sb1,m);
      sb2 += __shfl_xor(sb2,m);
      sa11+= __shfl_xor(sa11,m);
      sa12+= __shfl_xor(sa12,m);
      sa22+= __shfl_xor(sa22,m);
    }

    const float iz = 1.0f/z;
    const float ux = x*iz, vy = y*iz;
    const float m00=fx*iz, m01=0.f,    m02=-fx*ux*iz, m03=-fx*ux*vy,       m04=fx*(1.f+ux*ux), m05=-fx*vy;
    const float m10=0.f,   m11=fy*iz,  m12=-fy*vy*iz, m13=-fy*(1.f+vy*vy), m14=fy*ux*vy,       m15=fy*ux;

    float contrib;
    if(role==0){
      const float M0=sel6(ci,m00,m01,m02,m03,m04,m05);
      const float M1=sel6(ci,m10,m11,m12,m13,m14,m15);
      contrib = M0*sb1 + M1*sb2;
    } else if(role==1){
      const float M0i=sel6(ci,m00,m01,m02,m03,m04,m05);
      const float M1i=sel6(ci,m10,m11,m12,m13,m14,m15);
      const float M0j=sel6(cj,m00,m01,m02,m03,m04,m05);
      const float M1j=sel6(cj,m10,m11,m12,m13,m14,m15);
      contrib = sa11*(M0i*M0j) + sa12*(M0i*M1j + M1i*M0j) + sa22*(M1i*M1j);
    } else if(role==2){
      contrib = see;
    } else {
      contrib = 0.f;
    }
    acc += (double)contrib;
  }

  if(lane<28) wacc[wid][lane] = acc;
  __syncthreads();
  if(threadIdx.x<28){
    double s = wacc[0][threadIdx.x]+wacc[1][threadIdx.x]+wacc[2][threadIdx.x]+wacc[3][threadIdx.x];
    atomicAdd(&g_st.accA[threadIdx.x], s);
  }
}

__global__ __launch_bounds__(256) void k_cost(
    const float* __restrict__ pts, const float* __restrict__ ref,
    const float* __restrict__ Q,   const float* __restrict__ Kin)
{
  __shared__ double wacc[4];
  const int lane = threadIdx.x & 63;
  const int wid  = threadIdx.x >> 6;

  const float fx=Kin[0], cx=Kin[2], fy=Kin[4], cy=Kin[5];
  const float R00=g_st.Rc[0],R01=g_st.Rc[1],R02=g_st.Rc[2];
  const float R10=g_st.Rc[3],R11=g_st.Rc[4],R12=g_st.Rc[5];
  const float R20=g_st.Rc[6],R21=g_st.Rc[7],R22=g_st.Rc[8];
  const float t0=g_st.tc[0],t1=g_st.tc[1],t2=g_st.tc[2];

  double acc = 0.0;
  const int c0 = lane*2;
  const int wstride = gridDim.x*4;
  for(int n = blockIdx.x*4 + wid; n < NPTS; n += wstride){
    const float X=pts[3*n], Y=pts[3*n+1], Z=pts[3*n+2];
    const float x = R00*X + R01*Y + R02*Z + t0;
    const float y = R10*X + R11*Y + R12*Z + t1;
    const float z = R20*X + R21*Y + R22*Z + t2;
    const float uu = fx*x + cx*z;
    const float vv = fy*y + cy*z;
    const int pjx = (int)rintf(uu/z) - 1;
    const int pjy = (int)rintf(vv/z) - 1;
    const int jj = pjx<0?0:(pjx>(WIMG-1)?(WIMG-1):pjx);
    const int ii = pjy<0?0:(pjy>(HIMG-1)?(HIMG-1):pjy);
    const int idx = ii*WIMG + jj;

    const int o0 = c0*HWSZ + idx;
    const float q0 = Q[o0], q1 = Q[o0+HWSZ];
    const float2 rr = *reinterpret_cast<const float2*>(ref + n*CCH + c0);
    const float e0 = q0-rr.x, e1 = q1-rr.y;
    float see = e0*e0 + e1*e1;
    #pragma unroll
    for(int m=1;m<64;m<<=1) see += __shfl_xor(see,m);
    if(lane==0) acc += (double)see;
  }
  if(lane==0) wacc[wid]=acc;
  __syncthreads();
  if(threadIdx.x==0) atomicAdd(&g_st.accB, wacc[0]+wacc[1]+wacc[2]+wacc[3]);
}

__global__ void k_solve(int iter){
  if(threadIdx.x!=0) return;
  const double cost_mean = 0.5*g_st.accA[27]/(double)NPTS;
  if(iter==0) g_st.prev_cost = cost_mean;
  const double lam = (double)g_st.lam;

  double Hm[6][6];
  int m=0;
  for(int i=0;i<6;i++) for(int j=i;j<6;j++){ double v=g_st.accA[6+m]; m++; Hm[i][j]=v; Hm[j][i]=v; }
  double A[6][7];
  for(int i=0;i<6;i++){
    for(int j=0;j<6;j++) A[i][j]=Hm[i][j];
    A[i][i] = Hm[i][i] + lam*(Hm[i][i]+1e-9);
    A[i][6] = g_st.accA[i];
  }
  for(int k=0;k<6;k++){
    int piv=k; double mx=fabs(A[k][k]);
    for(int r=k+1;r<6;r++){ double v=fabs(A[r][k]); if(v>mx){mx=v;piv=r;} }
    if(piv!=k){ for(int c=k;c<7;c++){ double tmp=A[k][c]; A[k][c]=A[piv][c]; A[piv][c]=tmp; } }
    const double inv = 1.0/A[k][k];
    for(int r=k+1;r<6;r++){
      const double f = A[r][k]*inv;
      for(int c=k;c<7;c++) A[r][c] -= f*A[k][c];
    }
  }
  double xsol[6];
  for(int r=5;r>=0;r--){
    double s=A[r][6];
    for(int c=r+1;c<6;c++) s -= A[r][c]*xsol[c];
    xsol[r]=s/A[r][r];
  }
  const double lr = (double)g_st.lr;
  float d[6];
  for(int k=0;k<6;k++) d[k] = (float)(-lr*xsol[k]);

  const float wx=d[3], wy=d[4], wz=d[5];
  const float th2 = wx*wx+wy*wy+wz*wz;
  const float theta = sqrtf(th2);
  const bool small = theta < 1e-7f;
  const float th = small?1.0f:theta;
  const float Aa = small?1.0f:(sinf(th)/th);
  const float Bb = small?0.5f:((1.0f-cosf(th))/(th*th));
  float Wm[3][3] = {{0.f,-wz,wy},{wz,0.f,-wx},{-wy,wx,0.f}};
  float W2[3][3];
  for(int i=0;i<3;i++) for(int j=0;j<3;j++)
    W2[i][j] = Wm[i][0]*Wm[0][j] + Wm[i][1]*Wm[1][j] + Wm[i][2]*Wm[2][j];
  float dR[3][3];
  for(int i=0;i<3;i++) for(int j=0;j<3;j++)
    dR[i][j] = (i==j?1.f:0.f) + Aa*Wm[i][j] + Bb*W2[i][j];

  float Rn[9], tn[3];
  for(int i=0;i<3;i++){
    for(int j=0;j<3;j++)
      Rn[i*3+j] = dR[i][0]*g_st.R[0*3+j] + dR[i][1]*g_st.R[1*3+j] + dR[i][2]*g_st.R[2*3+j];
    tn[i] = dR[i][0]*g_st.t[0] + dR[i][1]*g_st.t[1] + dR[i][2]*g_st.t[2] + d[i];
  }
  for(int i=0;i<9;i++) g_st.Rc[i]=Rn[i];
  for(int i=0;i<3;i++) g_st.tc[i]=tn[i];
  g_st.accB = 0.0;
}

__global__ void k_update(){
  if(threadIdx.x!=0) return;
  const double new_cost = 0.5*g_st.accB/(double)NPTS;
  const bool worse = new_cost > g_st.prev_cost;
  float lam = g_st.lam * (worse?10.0f:0.1f);
  lam = fminf(fmaxf(lam,1e-6f),10000.0f);
  g_st.lam = lam;
  g_st.lr  = worse ? fminf(fmaxf(0.1f*g_st.lr,0.001f),1.0f) : 0.1f;
  if(!worse){
    for(int i=0;i<9;i++) g_st.R[i]=g_st.Rc[i];
    for(int i=0;i<3;i++) g_st.t[i]=g_st.tc[i];
    g_st.prev_cost = new_cost;
  }
  for(int i=0;i<28;i++) g_st.accA[i]=0.0;
}

__global__ void k_write(float* __restrict__ out, int out_size){
  const int i = threadIdx.x;
  if(i<9 && i<out_size) out[i]=g_st.R[i];
  else if(i<12 && i<out_size) out[i]=g_st.t[i-9];
}

extern "C" void kernel_launch(void* const* d_in, const int* in_sizes, int n_in,
                              void* d_out, int out_size, void* d_ws, size_t ws_size,
                              hipStream_t stream) {
  const float* pts = (const float*)d_in[0];
  const float* ref = (const float*)d_in[1];
  const float* Q   = (const float*)d_in[2];
  const float* GX  = (const float*)d_in[3];
  const float* GY  = (const float*)d_in[4];
  const float* Km  = (const float*)d_in[5];
  float* out = (float*)d_out;

  const size_t need = (size_t)HWSZ * TROW * sizeof(float); // ~472 MB
  const int GRID = 2048;

  if(d_ws != nullptr && ws_size >= need){
    float* T = (float*)d_ws;
    k_transpose<<<3*NTILE,256,0,stream>>>(Q,GX,GY,T);   // includes g_st init
    k_pass<<<GRID,256,0,stream>>>(pts,ref,T,Km,0);      // accums at initial pose -> slotsA
    for(int i=0;i<5;i++){
      k_step<<<1,64,0,stream>>>(i);                     // (update if i>0) + solve -> candidate
      k_pass<<<GRID,256,0,stream>>>(pts,ref,T,Km,1);    // fused cost+accums at candidate -> slotsC
    }
    k_finish<<<1,64,0,stream>>>(out,out_size);          // final accept/reject + write
  } else {
    // fallback: verified legacy path (no workspace layout transform)
    k_init<<<1,64,0,stream>>>();
    for(int i=0;i<5;i++){
      k_accum<<<GRID,256,0,stream>>>(pts,ref,Q,GX,GY,Km);
      k_solve<<<1,64,0,stream>>>(i);
      k_cost<<<GRID,256,0,stream>>>(pts,ref,Q,Km);
      k_update<<<1,64,0,stream>>>();
    }
    k_write<<<1,64,0,stream>>>(out,out_size);
  }
}

// Round 4
// 865.524 us; speedup vs baseline: 5.2145x; 1.1531x over previous
//
#include <hip/hip_runtime.h>

#define NPTS 100000
#define CCH  128
#define HIMG 480
#define WIMG 640
#define HWSZ (HIMG*WIMG)
// transposed layout: per pixel 384 floats = 32 groups of 12: [q(4c)|gx(4c)|gy(4c)]
// map m, channel c  ->  float offset 12*(c>>2) + 4*m + (c&3)
#define TROW 384
#define NSLOT 8

struct State {
  double slotsA[NSLOT][28]; // accepted-pose accums: [0..5]=g, [6..26]=H ut, [27]=ee
  double slotsC[NSLOT][28]; // candidate-pose accums
  double accA[28];          // legacy fallback
  double accB;              // legacy fallback
  double prev_cost;
  float R[9];
  float t[3];
  float Rc[9];
  float tc[3];
  float lam;
  float lr;
};

__device__ State g_st;

// upper-tri index
#define HIDX(i,j) (6 + (6*(i)) - ((i)*((i)-1))/2 + ((j)-(i)))

__device__ __forceinline__ float sel6(int k, float a0,float a1,float a2,float a3,float a4,float a5){
  float r = a0;
  r = (k==1)?a1:r; r = (k==2)?a2:r; r = (k==3)?a3:r; r = (k==4)?a4:r; r = (k==5)?a5:r;
  return r;
}

// ---------------------------------------------------------------------------
// Transpose (C,H,W) x3 -> (pixel, 384) group-interleaved. 32 pixels per block,
// ALL THREE maps per block (required for interleaved output rows).
// LDS [pixel][392] with float4-granular XOR swizzle keyed by (p>>2)&3:
// same-channel lanes (differing only in pixel) spread across 4 banks.
// Block 0 / thread 0 also (re)initializes g_st.
// ---------------------------------------------------------------------------
#define TP_PIX 32
#define NTILE (HWSZ/TP_PIX)   // 9600
#define TROWP 392
#define TIX(p,fo) ((p)*TROWP + ((fo) ^ ((((p)>>2)&3)<<2)))

__global__ __launch_bounds__(256) void k_transpose(
    const float* __restrict__ Q, const float* __restrict__ GX,
    const float* __restrict__ GY, float* __restrict__ T)
{
  if(blockIdx.x==0 && threadIdx.x==0){
    for(int s=0;s<NSLOT;s++) for(int k=0;k<28;k++){ g_st.slotsA[s][k]=0.0; g_st.slotsC[s][k]=0.0; }
    g_st.prev_cost=0.0;
    g_st.R[0]=1.f; g_st.R[1]=0.f; g_st.R[2]=0.f;
    g_st.R[3]=0.f; g_st.R[4]=1.f; g_st.R[5]=0.f;
    g_st.R[6]=0.f; g_st.R[7]=0.f; g_st.R[8]=1.f;
    g_st.t[0]=1.f; g_st.t[1]=1.f; g_st.t[2]=0.f;
    g_st.lam=0.01f; g_st.lr=0.1f;
  }

  __shared__ __align__(16) float tile[TP_PIX*TROWP];   // 50176 B
  const int pbase = blockIdx.x * TP_PIX;
  const int t = threadIdx.x;

  // load: 3 maps x 128 ch x 32 px, float4 = 4 pixels of one channel.
  // per wave-instr: 8 channels x 128B segments.
  const int c_lo = t>>3;          // 0..31
  const int px4  = (t&7)<<2;      // 0,4,...,28
  #pragma unroll
  for(int j=0;j<12;j++){
    const int m = j>>2;
    const float* __restrict__ src = (m==0)?Q:((m==1)?GX:GY);
    const int c = c_lo + 32*(j&3);
    const float4 v = *reinterpret_cast<const float4*>(src + (size_t)c*HWSZ + pbase + px4);
    const int fo = 12*(c>>2) + 4*m + (c&3);
    tile[TIX(px4+0,fo)] = v.x;
    tile[TIX(px4+1,fo)] = v.y;
    tile[TIX(px4+2,fo)] = v.z;
    tile[TIX(px4+3,fo)] = v.w;
  }
  __syncthreads();
  // store: thread t owns pixel p=t>>3; 8 lanes cover 128B contiguous per chunk.
  const int p = t>>3;             // 0..31
  const int s = t&7;
  float* dstp = T + (size_t)(pbase+p)*TROW;
  #pragma unroll
  for(int j=0;j<12;j++){
    const int fo = 4*(s + 8*j);   // 0..380
    const float4 v = *reinterpret_cast<const float4*>(&tile[TIX(p,fo)]);
    *reinterpret_cast<float4*>(dstp + fo) = v;
  }
}

// ---------------------------------------------------------------------------
// Pass: TWO points per wave (lanes 0-31 = point A, 32-63 = point B), each lane
// owns 4 channels (3 aligned float4 gathers + float4 ref). Per-lane fp32
// accumulation of all 28 components; zero cross-lane ops in the loop.
// One double butterfly (sums both halves = both points) at kernel end.
// ---------------------------------------------------------------------------
__global__ __launch_bounds__(256) void k_pass(
    const float* __restrict__ pts, const float* __restrict__ ref,
    const float* __restrict__ T,   const float* __restrict__ Kin, int cand)
{
  __shared__ double wacc[4][28];
  const int lane = threadIdx.x & 63;
  const int wid  = threadIdx.x >> 6;
  const int h = lane >> 5;      // which point of the pair
  const int l = lane & 31;      // 4-channel group

  const float fx=Kin[0], cx=Kin[2], fy=Kin[4], cy=Kin[5];
  const float* Rp = cand ? g_st.Rc : g_st.R;
  const float* tp = cand ? g_st.tc : g_st.t;
  const float R00=Rp[0],R01=Rp[1],R02=Rp[2];
  const float R10=Rp[3],R11=Rp[4],R12=Rp[5];
  const float R20=Rp[6],R21=Rp[7],R22=Rp[8];
  const float t0=tp[0],t1=tp[1],t2=tp[2];

  float a[28];
  #pragma unroll
  for(int k=0;k<28;k++) a[k]=0.f;

  const int NPAIR = NPTS/2;     // 50000, NPTS even -> no per-lane tail mask
  const int wstride = gridDim.x*4;
  for(int pp = blockIdx.x*4 + wid; pp < NPAIR; pp += wstride){
    const int n = 2*pp + h;
    const float X=pts[3*n], Y=pts[3*n+1], Z=pts[3*n+2];
    const float x = R00*X + R01*Y + R02*Z + t0;
    const float y = R10*X + R11*Y + R12*Z + t1;
    const float z = R20*X + R21*Y + R22*Z + t2;
    const float uu = fx*x + cx*z;
    const float vv = fy*y + cy*z;
    const int pjx = (int)rintf(uu/z) - 1;
    const int pjy = (int)rintf(vv/z) - 1;
    const int jj = pjx<0?0:(pjx>(WIMG-1)?(WIMG-1):pjx);
    const int ii = pjy<0?0:(pjy>(HIMG-1)?(HIMG-1):pjy);
    const int idx = ii*WIMG + jj;

    const float* base = T + (size_t)idx*TROW + 12*l;
    const float4 qq = *reinterpret_cast<const float4*>(base);
    const float4 gx = *reinterpret_cast<const float4*>(base+4);
    const float4 gy = *reinterpret_cast<const float4*>(base+8);
    const float4 rr = *reinterpret_cast<const float4*>(ref + (size_t)n*CCH + 4*l);

    const float e0=qq.x-rr.x, e1=qq.y-rr.y, e2=qq.z-rr.z, e3=qq.w-rr.w;
    const float see = e0*e0+e1*e1+e2*e2+e3*e3;
    const float sb1 = gx.x*e0+gx.y*e1+gx.z*e2+gx.w*e3;
    const float sb2 = gy.x*e0+gy.y*e1+gy.z*e2+gy.w*e3;
    const float sa11= gx.x*gx.x+gx.y*gx.y+gx.z*gx.z+gx.w*gx.w;
    const float sa12= gx.x*gy.x+gx.y*gy.y+gx.z*gy.z+gx.w*gy.w;
    const float sa22= gy.x*gy.x+gy.y*gy.y+gy.z*gy.z+gy.w*gy.w;

    // M (2x6), per-lane (own point); M0[1]=M1[0]=0 elided
    const float iz = 1.0f/z;
    const float ux = x*iz, vy = y*iz;
    const float m00=fx*iz,  m02=-fx*ux*iz, m03=-fx*ux*vy,       m04=fx*(1.f+ux*ux), m05=-fx*vy;
    const float m11=fy*iz,  m12=-fy*vy*iz, m13=-fy*(1.f+vy*vy), m14=fy*ux*vy,       m15=fy*ux;

    // g += M^T [sb1;sb2]
    a[0] += m00*sb1;
    a[1] += m11*sb2;
    a[2] += m02*sb1 + m12*sb2;
    a[3] += m03*sb1 + m13*sb2;
    a[4] += m04*sb1 + m14*sb2;
    a[5] += m05*sb1 + m15*sb2;

    // P = S*M (2x6), S = [[sa11,sa12],[sa12,sa22]]
    const float p00 = sa11*m00;
    const float p10 = sa12*m00;
    const float p01 = sa12*m11;
    const float p11 = sa22*m11;
    const float p02 = sa11*m02 + sa12*m12;
    const float p12 = sa12*m02 + sa22*m12;
    const float p03 = sa11*m03 + sa12*m13;
    const float p13 = sa12*m03 + sa22*m13;
    const float p04 = sa11*m04 + sa12*m14;
    const float p14 = sa12*m04 + sa22*m14;
    const float p05 = sa11*m05 + sa12*m15;
    const float p15 = sa12*m05 + sa22*m15;

    // H(i,j) += P0_i*M0[j] + P1_i*M1[j]  (upper-tri)
    a[HIDX(0,0)] += p00*m00;
    a[HIDX(0,1)] += p10*m11;
    a[HIDX(0,2)] += p00*m02 + p10*m12;
    a[HIDX(0,3)] += p00*m03 + p10*m13;
    a[HIDX(0,4)] += p00*m04 + p10*m14;
    a[HIDX(0,5)] += p00*m05 + p10*m15;
    a[HIDX(1,1)] += p11*m11;
    a[HIDX(1,2)] += p01*m02 + p11*m12;
    a[HIDX(1,3)] += p01*m03 + p11*m13;
    a[HIDX(1,4)] += p01*m04 + p11*m14;
    a[HIDX(1,5)] += p01*m05 + p11*m15;
    a[HIDX(2,2)] += p02*m02 + p12*m12;
    a[HIDX(2,3)] += p02*m03 + p12*m13;
    a[HIDX(2,4)] += p02*m04 + p12*m14;
    a[HIDX(2,5)] += p02*m05 + p12*m15;
    a[HIDX(3,3)] += p03*m03 + p13*m13;
    a[HIDX(3,4)] += p03*m04 + p13*m14;
    a[HIDX(3,5)] += p03*m05 + p13*m15;
    a[HIDX(4,4)] += p04*m04 + p14*m14;
    a[HIDX(4,5)] += p04*m05 + p14*m15;
    a[HIDX(5,5)] += p05*m05 + p15*m15;
    a[27] += see;
  }

  // once-per-kernel reduction: double butterfly (sums both halves), block sum
  #pragma unroll
  for(int k=0;k<28;k++){
    double v = (double)a[k];
    #pragma unroll
    for(int m=1;m<64;m<<=1) v += __shfl_xor(v,m);
    if(lane==0) wacc[wid][k]=v;
  }
  __syncthreads();
  if(threadIdx.x<28){
    double s = wacc[0][threadIdx.x]+wacc[1][threadIdx.x]+wacc[2][threadIdx.x]+wacc[3][threadIdx.x];
    double* slot = cand ? g_st.slotsC[blockIdx.x & (NSLOT-1)] : g_st.slotsA[blockIdx.x & (NSLOT-1)];
    atomicAdd(&slot[threadIdx.x], s);
  }
}

// ---------------------------------------------------------------------------
// Fused step: (iter>0: LM accept/reject from slotsC) then solve -> candidate.
// ---------------------------------------------------------------------------
__global__ void k_step(int iter){
  __shared__ double red[28];
  __shared__ double sC[28];
  const int t = threadIdx.x;
  if(t<28){
    double c=0.0, aa=0.0;
    for(int s=0;s<NSLOT;s++){ c += g_st.slotsC[s][t]; aa += g_st.slotsA[s][t]; }
    sC[t]=c; red[t]=aa;
  }
  __syncthreads();
  if(t!=0) return;

  if(iter>0){
    const double new_cost = 0.5*sC[27]/(double)NPTS;
    const bool worse = new_cost > g_st.prev_cost;
    float lam = g_st.lam * (worse?10.0f:0.1f);
    g_st.lam = fminf(fmaxf(lam,1e-6f),10000.0f);
    g_st.lr  = worse ? fminf(fmaxf(0.1f*g_st.lr,0.001f),1.0f) : 0.1f;
    if(!worse){
      for(int k=0;k<28;k++){
        red[k]=sC[k];
        g_st.slotsA[0][k]=sC[k];
        for(int s=1;s<NSLOT;s++) g_st.slotsA[s][k]=0.0;
      }
      for(int i=0;i<9;i++) g_st.R[i]=g_st.Rc[i];
      for(int i=0;i<3;i++) g_st.t[i]=g_st.tc[i];
      g_st.prev_cost = new_cost;
    }
    for(int s=0;s<NSLOT;s++) for(int k=0;k<28;k++) g_st.slotsC[s][k]=0.0;
  } else {
    g_st.prev_cost = 0.5*red[27]/(double)NPTS;
  }

  const double lam = (double)g_st.lam;
  double Hm[6][6];
  int m=0;
  for(int i=0;i<6;i++) for(int j=i;j<6;j++){ double v=red[6+m]; m++; Hm[i][j]=v; Hm[j][i]=v; }
  double A[6][7];
  for(int i=0;i<6;i++){
    for(int j=0;j<6;j++) A[i][j]=Hm[i][j];
    A[i][i] = Hm[i][i] + lam*(Hm[i][i]+1e-9);
    A[i][6] = red[i];
  }
  for(int k=0;k<6;k++){
    int piv=k; double mx=fabs(A[k][k]);
    for(int r=k+1;r<6;r++){ double v=fabs(A[r][k]); if(v>mx){mx=v;piv=r;} }
    if(piv!=k){ for(int c=k;c<7;c++){ double tmp=A[k][c]; A[k][c]=A[piv][c]; A[piv][c]=tmp; } }
    const double inv = 1.0/A[k][k];
    for(int r=k+1;r<6;r++){
      const double f = A[r][k]*inv;
      for(int c=k;c<7;c++) A[r][c] -= f*A[k][c];
    }
  }
  double xsol[6];
  for(int r=5;r>=0;r--){
    double s=A[r][6];
    for(int c=r+1;c<6;c++) s -= A[r][c]*xsol[c];
    xsol[r]=s/A[r][r];
  }
  const double lr = (double)g_st.lr;
  float d[6];
  for(int k=0;k<6;k++) d[k] = (float)(-lr*xsol[k]);

  const float wx=d[3], wy=d[4], wz=d[5];
  const float th2 = wx*wx+wy*wy+wz*wz;
  const float theta = sqrtf(th2);
  const bool small = theta < 1e-7f;
  const float th = small?1.0f:theta;
  const float Aa = small?1.0f:(sinf(th)/th);
  const float Bb = small?0.5f:((1.0f-cosf(th))/(th*th));
  float Wm[3][3] = {{0.f,-wz,wy},{wz,0.f,-wx},{-wy,wx,0.f}};
  float W2[3][3];
  for(int i=0;i<3;i++) for(int j=0;j<3;j++)
    W2[i][j] = Wm[i][0]*Wm[0][j] + Wm[i][1]*Wm[1][j] + Wm[i][2]*Wm[2][j];
  float dR[3][3];
  for(int i=0;i<3;i++) for(int j=0;j<3;j++)
    dR[i][j] = (i==j?1.f:0.f) + Aa*Wm[i][j] + Bb*W2[i][j];

  float Rn[9], tn[3];
  for(int i=0;i<3;i++){
    for(int j=0;j<3;j++)
      Rn[i*3+j] = dR[i][0]*g_st.R[0*3+j] + dR[i][1]*g_st.R[1*3+j] + dR[i][2]*g_st.R[2*3+j];
    tn[i] = dR[i][0]*g_st.t[0] + dR[i][1]*g_st.t[1] + dR[i][2]*g_st.t[2] + d[i];
  }
  for(int i=0;i<9;i++) g_st.Rc[i]=Rn[i];
  for(int i=0;i<3;i++) g_st.tc[i]=tn[i];
}

// Final: accept/reject last candidate, write output.
__global__ void k_finish(float* __restrict__ out, int out_size){
  const int t = threadIdx.x;
  if(t==0){
    double c=0.0; for(int s=0;s<NSLOT;s++) c += g_st.slotsC[s][27];
    const double new_cost = 0.5*c/(double)NPTS;
    if(!(new_cost > g_st.prev_cost)){
      for(int i=0;i<9;i++) g_st.R[i]=g_st.Rc[i];
      for(int i=0;i<3;i++) g_st.t[i]=g_st.tc[i];
    }
  }
  __syncthreads();
  if(t<9 && t<out_size) out[t]=g_st.R[t];
  else if(t<12 && t<out_size) out[t]=g_st.t[t-9];
}

// ---------------------------------------------------------------------------
// Legacy fallback path (verified): direct (C,H,W) gathers, no workspace.
// ---------------------------------------------------------------------------
__global__ void k_init(){
  if(threadIdx.x==0){
    for(int i=0;i<28;i++) g_st.accA[i]=0.0;
    g_st.accB=0.0; g_st.prev_cost=0.0;
    g_st.R[0]=1.f; g_st.R[1]=0.f; g_st.R[2]=0.f;
    g_st.R[3]=0.f; g_st.R[4]=1.f; g_st.R[5]=0.f;
    g_st.R[6]=0.f; g_st.R[7]=0.f; g_st.R[8]=1.f;
    g_st.t[0]=1.f; g_st.t[1]=1.f; g_st.t[2]=0.f;
    g_st.lam=0.01f; g_st.lr=0.1f;
  }
}

__global__ __launch_bounds__(256) void k_accum(
    const float* __restrict__ pts, const float* __restrict__ ref,
    const float* __restrict__ Q,   const float* __restrict__ GX,
    const float* __restrict__ GY,  const float* __restrict__ Kin)
{
  __shared__ double wacc[4][28];
  const int lane = threadIdx.x & 63;
  const int wid  = threadIdx.x >> 6;

  const float fx=Kin[0], cx=Kin[2], fy=Kin[4], cy=Kin[5];
  const float R00=g_st.R[0],R01=g_st.R[1],R02=g_st.R[2];
  const float R10=g_st.R[3],R11=g_st.R[4],R12=g_st.R[5];
  const float R20=g_st.R[6],R21=g_st.R[7],R22=g_st.R[8];
  const float t0=g_st.t[0],t1=g_st.t[1],t2=g_st.t[2];

  int role = 3, ci = 0, cj = 0;
  if(lane < 6){ role = 0; ci = lane; cj = lane; }
  else if(lane < 27){
    role = 1;
    const int tt = lane - 6;
    int i = 5;
    i = (tt < 20) ? 4 : i;
    i = (tt < 18) ? 3 : i;
    i = (tt < 15) ? 2 : i;
    i = (tt < 11) ? 1 : i;
    i = (tt <  6) ? 0 : i;
    const int rs = (i==0)?0:(i==1)?6:(i==2)?11:(i==3)?15:(i==4)?18:20;
    ci = i; cj = i + (tt - rs);
  }
  else if(lane == 27){ role = 2; }

  double acc = 0.0;
  const int c0 = lane*2;
  const int wstride = gridDim.x*4;
  for(int n = blockIdx.x*4 + wid; n < NPTS; n += wstride){
    const float X=pts[3*n], Y=pts[3*n+1], Z=pts[3*n+2];
    const float x = R00*X + R01*Y + R02*Z + t0;
    const float y = R10*X + R11*Y + R12*Z + t1;
    const float z = R20*X + R21*Y + R22*Z + t2;
    const float uu = fx*x + cx*z;
    const float vv = fy*y + cy*z;
    const int pjx = (int)rintf(uu/z) - 1;
    const int pjy = (int)rintf(vv/z) - 1;
    const int jj = pjx<0?0:(pjx>(WIMG-1)?(WIMG-1):pjx);
    const int ii = pjy<0?0:(pjy>(HIMG-1)?(HIMG-1):pjy);
    const int idx = ii*WIMG + jj;

    const int o0 = c0*HWSZ + idx;
    const float q0 = Q[o0],  q1 = Q[o0+HWSZ];
    const float gx0= GX[o0], gx1= GX[o0+HWSZ];
    const float gy0= GY[o0], gy1= GY[o0+HWSZ];
    const float2 rr = *reinterpret_cast<const float2*>(ref + n*CCH + c0);
    const float e0 = q0-rr.x, e1 = q1-rr.y;

    float see = e0*e0 + e1*e1;
    float sb1 = gx0*e0 + gx1*e1;
    float sb2 = gy0*e0 + gy1*e1;
    float sa11= gx0*gx0 + gx1*gx1;
    float sa12= gx0*gy0 + gx1*gy1;
    float sa22= gy0*gy0 + gy1*gy1;
    #pragma unroll
    for(int m=1;m<64;m<<=1){
      see += __shfl_xor(see,m);
      sb1 += __shfl_xor(sb1,m);
      sb2 += __shfl_xor(sb2,m);
      sa11+= __shfl_xor(sa11,m);
      sa12+= __shfl_xor(sa12,m);
      sa22+= __shfl_xor(sa22,m);
    }

    const float iz = 1.0f/z;
    const float ux = x*iz, vy = y*iz;
    const float m00=fx*iz, m01=0.f,    m02=-fx*ux*iz, m03=-fx*ux*vy,       m04=fx*(1.f+ux*ux), m05=-fx*vy;
    const float m10=0.f,   m11=fy*iz,  m12=-fy*vy*iz, m13=-fy*(1.f+vy*vy), m14=fy*ux*vy,       m15=fy*ux;

    float contrib;
    if(role==0){
      const float M0=sel6(ci,m00,m01,m02,m03,m04,m05);
      const float M1=sel6(ci,m10,m11,m12,m13,m14,m15);
      contrib = M0*sb1 + M1*sb2;
    } else if(role==1){
      const float M0i=sel6(ci,m00,m01,m02,m03,m04,m05);
      const float M1i=sel6(ci,m10,m11,m12,m13,m14,m15);
      const float M0j=sel6(cj,m00,m01,m02,m03,m04,m05);
      const float M1j=sel6(cj,m10,m11,m12,m13,m14,m15);
      contrib = sa11*(M0i*M0j) + sa12*(M0i*M1j + M1i*M0j) + sa22*(M1i*M1j);
    } else if(role==2){
      contrib = see;
    } else {
      contrib = 0.f;
    }
    acc += (double)contrib;
  }

  if(lane<28) wacc[wid][lane] = acc;
  __syncthreads();
  if(threadIdx.x<28){
    double s = wacc[0][threadIdx.x]+wacc[1][threadIdx.x]+wacc[2][threadIdx.x]+wacc[3][threadIdx.x];
    atomicAdd(&g_st.accA[threadIdx.x], s);
  }
}

__global__ __launch_bounds__(256) void k_cost(
    const float* __restrict__ pts, const float* __restrict__ ref,
    const float* __restrict__ Q,   const float* __restrict__ Kin)
{
  __shared__ double wacc[4];
  const int lane = threadIdx.x & 63;
  const int wid  = threadIdx.x >> 6;

  const float fx=Kin[0], cx=Kin[2], fy=Kin[4], cy=Kin[5];
  const float R00=g_st.Rc[0],R01=g_st.Rc[1],R02=g_st.Rc[2];
  const float R10=g_st.Rc[3],R11=g_st.Rc[4],R12=g_st.Rc[5];
  const float R20=g_st.Rc[6],R21=g_st.Rc[7],R22=g_st.Rc[8];
  const float t0=g_st.tc[0],t1=g_st.tc[1],t2=g_st.tc[2];

  double acc = 0.0;
  const int c0 = lane*2;
  const int wstride = gridDim.x*4;
  for(int n = blockIdx.x*4 + wid; n < NPTS; n += wstride){
    const float X=pts[3*n], Y=pts[3*n+1], Z=pts[3*n+2];
    const float x = R00*X + R01*Y + R02*Z + t0;
    const float y = R10*X + R11*Y + R12*Z + t1;
    const float z = R20*X + R21*Y + R22*Z + t2;
    const float uu = fx*x + cx*z;
    const float vv = fy*y + cy*z;
    const int pjx = (int)rintf(uu/z) - 1;
    const int pjy = (int)rintf(vv/z) - 1;
    const int jj = pjx<0?0:(pjx>(WIMG-1)?(WIMG-1):pjx);
    const int ii = pjy<0?0:(pjy>(HIMG-1)?(HIMG-1):pjy);
    const int idx = ii*WIMG + jj;

    const int o0 = c0*HWSZ + idx;
    const float q0 = Q[o0], q1 = Q[o0+HWSZ];
    const float2 rr = *reinterpret_cast<const float2*>(ref + n*CCH + c0);
    const float e0 = q0-rr.x, e1 = q1-rr.y;
    float see = e0*e0 + e1*e1;
    #pragma unroll
    for(int m=1;m<64;m<<=1) see += __shfl_xor(see,m);
    if(lane==0) acc += (double)see;
  }
  if(lane==0) wacc[wid]=acc;
  __syncthreads();
  if(threadIdx.x==0) atomicAdd(&g_st.accB, wacc[0]+wacc[1]+wacc[2]+wacc[3]);
}

__global__ void k_solve(int iter){
  if(threadIdx.x!=0) return;
  const double cost_mean = 0.5*g_st.accA[27]/(double)NPTS;
  if(iter==0) g_st.prev_cost = cost_mean;
  const double lam = (double)g_st.lam;

  double Hm[6][6];
  int m=0;
  for(int i=0;i<6;i++) for(int j=i;j<6;j++){ double v=g_st.accA[6+m]; m++; Hm[i][j]=v; Hm[j][i]=v; }
  double A[6][7];
  for(int i=0;i<6;i++){
    for(int j=0;j<6;j++) A[i][j]=Hm[i][j];
    A[i][i] = Hm[i][i] + lam*(Hm[i][i]+1e-9);
    A[i][6] = g_st.accA[i];
  }
  for(int k=0;k<6;k++){
    int piv=k; double mx=fabs(A[k][k]);
    for(int r=k+1;r<6;r++){ double v=fabs(A[r][k]); if(v>mx){mx=v;piv=r;} }
    if(piv!=k){ for(int c=k;c<7;c++){ double tmp=A[k][c]; A[k][c]=A[piv][c]; A[piv][c]=tmp; } }
    const double inv = 1.0/A[k][k];
    for(int r=k+1;r<6;r++){
      const double f = A[r][k]*inv;
      for(int c=k;c<7;c++) A[r][c] -= f*A[k][c];
    }
  }
  double xsol[6];
  for(int r=5;r>=0;r--){
    double s=A[r][6];
    for(int c=r+1;c<6;c++) s -= A[r][c]*xsol[c];
    xsol[r]=s/A[r][r];
  }
  const double lr = (double)g_st.lr;
  float d[6];
  for(int k=0;k<6;k++) d[k] = (float)(-lr*xsol[k]);

  const float wx=d[3], wy=d[4], wz=d[5];
  const float th2 = wx*wx+wy*wy+wz*wz;
  const float theta = sqrtf(th2);
  const bool small = theta < 1e-7f;
  const float th = small?1.0f:theta;
  const float Aa = small?1.0f:(sinf(th)/th);
  const float Bb = small?0.5f:((1.0f-cosf(th))/(th*th));
  float Wm[3][3] = {{0.f,-wz,wy},{wz,0.f,-wx},{-wy,wx,0.f}};
  float W2[3][3];
  for(int i=0;i<3;i++) for(int j=0;j<3;j++)
    W2[i][j] = Wm[i][0]*Wm[0][j] + Wm[i][1]*Wm[1][j] + Wm[i][2]*Wm[2][j];
  float dR[3][3];
  for(int i=0;i<3;i++) for(int j=0;j<3;j++)
    dR[i][j] = (i==j?1.f:0.f) + Aa*Wm[i][j] + Bb*W2[i][j];

  float Rn[9], tn[3];
  for(int i=0;i<3;i++){
    for(int j=0;j<3;j++)
      Rn[i*3+j] = dR[i][0]*g_st.R[0*3+j] + dR[i][1]*g_st.R[1*3+j] + dR[i][2]*g_st.R[2*3+j];
    tn[i] = dR[i][0]*g_st.t[0] + dR[i][1]*g_st.t[1] + dR[i][2]*g_st.t[2] + d[i];
  }
  for(int i=0;i<9;i++) g_st.Rc[i]=Rn[i];
  for(int i=0;i<3;i++) g_st.tc[i]=tn[i];
  g_st.accB = 0.0;
}

__global__ void k_update(){
  if(threadIdx.x!=0) return;
  const double new_cost = 0.5*g_st.accB/(double)NPTS;
  const bool worse = new_cost > g_st.prev_cost;
  float lam = g_st.lam * (worse?10.0f:0.1f);
  lam = fminf(fmaxf(lam,1e-6f),10000.0f);
  g_st.lam = lam;
  g_st.lr  = worse ? fminf(fmaxf(0.1f*g_st.lr,0.001f),1.0f) : 0.1f;
  if(!worse){
    for(int i=0;i<9;i++) g_st.R[i]=g_st.Rc[i];
    for(int i=0;i<3;i++) g_st.t[i]=g_st.tc[i];
    g_st.prev_cost = new_cost;
  }
  for(int i=0;i<28;i++) g_st.accA[i]=0.0;
}

__global__ void k_write(float* __restrict__ out, int out_size){
  const int i = threadIdx.x;
  if(i<9 && i<out_size) out[i]=g_st.R[i];
  else if(i<12 && i<out_size) out[i]=g_st.t[i-9];
}

extern "C" void kernel_launch(void* const* d_in, const int* in_sizes, int n_in,
                              void* d_out, int out_size, void* d_ws, size_t ws_size,
                              hipStream_t stream) {
  const float* pts = (const float*)d_in[0];
  const float* ref = (const float*)d_in[1];
  const float* Q   = (const float*)d_in[2];
  const float* GX  = (const float*)d_in[3];
  const float* GY  = (const float*)d_in[4];
  const float* Km  = (const float*)d_in[5];
  float* out = (float*)d_out;

  const size_t need = (size_t)HWSZ * TROW * sizeof(float); // ~472 MB
  const int GRID = 2048;

  if(d_ws != nullptr && ws_size >= need){
    float* T = (float*)d_ws;
    k_transpose<<<NTILE,256,0,stream>>>(Q,GX,GY,T);     // includes g_st init
    k_pass<<<GRID,256,0,stream>>>(pts,ref,T,Km,0);      // accums at initial pose -> slotsA
    for(int i=0;i<5;i++){
      k_step<<<1,64,0,stream>>>(i);                     // (update if i>0) + solve -> candidate
      k_pass<<<GRID,256,0,stream>>>(pts,ref,T,Km,1);    // fused cost+accums at candidate -> slotsC
    }
    k_finish<<<1,64,0,stream>>>(out,out_size);          // final accept/reject + write
  } else {
    // fallback: verified legacy path (no workspace layout transform)
    k_init<<<1,64,0,stream>>>();
    for(int i=0;i<5;i++){
      k_accum<<<GRID,256,0,stream>>>(pts,ref,Q,GX,GY,Km);
      k_solve<<<1,64,0,stream>>>(i);
      k_cost<<<GRID,256,0,stream>>>(pts,ref,Q,Km);
      k_update<<<1,64,0,stream>>>();
    }
    k_write<<<1,64,0,stream>>>(out,out_size);
  }
}